// Round 7
// baseline (456.965 us; speedup 1.0000x reference)
//
#include <hip/hip_runtime.h>
#include <hip/hip_bf16.h>

#define NDIM 128
#define SCAN_CHUNK 1024  // per block: 256 threads x 4 elements

typedef __attribute__((ext_vector_type(8))) short short8;
typedef __attribute__((ext_vector_type(4))) float f32x4;

__device__ __forceinline__ float bf2f(__hip_bfloat16 v) { return __bfloat162float(v); }

__device__ __forceinline__ float ldf(const void* p, long i, int f32) {
    return f32 ? ((const float*)p)[i] : bf2f(((const __hip_bfloat16*)p)[i]);
}
__device__ __forceinline__ void stf(void* p, long i, int f32, float v) {
    if (f32) ((float*)p)[i] = v;
    else     ((__hip_bfloat16*)p)[i] = __float2bfloat16(v);
}
__device__ __forceinline__ short f2bf(float v) {
    __hip_bfloat16 h = __float2bfloat16(v);
    short s;
    __builtin_memcpy(&s, &h, 2);
    return s;
}
// bf16x2 packed in a uint: low halfword = even feature, high = odd feature
__device__ __forceinline__ float bflo(unsigned u) { u <<= 16; float f; __builtin_memcpy(&f, &u, 4); return f; }
__device__ __forceinline__ float bfhi(unsigned u) { u &= 0xffff0000u; float f; __builtin_memcpy(&f, &u, 4); return f; }
__device__ __forceinline__ unsigned packbf(float a, float b) {
    unsigned la = (unsigned short)f2bf(a);
    unsigned hb = (unsigned short)f2bf(b);
    return (hb << 16) | la;
}
// Swizzled LDS index (shorts) for A-tiles: 16B-chunk XOR by (row&7).
__device__ __forceinline__ int aswz(int m, int k) {
    return m * NDIM + ((((k >> 3) ^ (m & 7)) << 3) | (k & 7));
}
// Same swizzle at uint (bf16x2) granularity: p = feature-pair index 0..63.
__device__ __forceinline__ int wswz(int m, int p) {
    return m * 64 + ((((p >> 2) ^ (m & 7)) << 2) | (p & 3));
}

// ---- detect dtypes + zero cnt/accum/npos -----------------------------------
__global__ void detect_kernel(const int* __restrict__ xedge32,
                              const unsigned int* __restrict__ yw,
                              const unsigned short* __restrict__ xh,
                              int* __restrict__ flags, int* __restrict__ cnt,
                              float* __restrict__ accum, int* __restrict__ npos, int N) {
    const int gid = blockIdx.x * 256 + threadIdx.x;
    for (int i = gid; i < N; i += gridDim.x * 256) cnt[i] = 0;
    if (gid == 0) { accum[0] = 0.f; accum[1] = 0.f; npos[0] = 0; }
    if (blockIdx.x == 0) {
        __shared__ int se, sy, scount;
        const int t = threadIdx.x;
        if (t == 0) { se = 1; sy = 0; scount = 0; }
        __syncthreads();
        for (int i = t; i < 512; i += 256)
            if (xedge32[2 * i + 1] != 0) se = 0;
        for (int i = t; i < 1024; i += 256)
            if (yw[i] > 1u) sy = 1;
        int c = 0;
        for (int i = t; i < 1024; i += 256) {
            int ex = (xh[2 * i] >> 7) & 0xFF;
            if (ex >= 100 && ex <= 150) c++;
        }
        atomicAdd(&scount, c);
        __syncthreads();
        if (t == 0) { flags[0] = se; flags[1] = sy; flags[2] = (scount < 900) ? 1 : 0; }
    }
}

// ---- prep: bf16-transposed weights + fp32 biases + canonical bf16x2 x ------

__global__ void prep_kernel(const void* __restrict__ x,
                            const void* __restrict__ W1l, const void* __restrict__ b1l,
                            const void* __restrict__ W1r, const void* __restrict__ W2l,
                            const void* __restrict__ b2l, const void* __restrict__ W2r,
                            const void* __restrict__ Wd, const int* __restrict__ flags,
                            short* __restrict__ T1l, short* __restrict__ T1r,
                            short* __restrict__ T2l, short* __restrict__ T2r,
                            short* __restrict__ Td, float* __restrict__ b1c,
                            float* __restrict__ b2c, unsigned* __restrict__ xb, int N) {
    const int wf = flags[2];
    const long idx = (long)blockIdx.x * 256 + threadIdx.x;
    if (idx < NDIM * NDIM) {
        int k = (int)(idx >> 7), n = (int)(idx & 127);
        int o = n * NDIM + k;
        T1l[o] = f2bf(ldf(W1l, idx, wf));
        T1r[o] = f2bf(ldf(W1r, idx, wf));
        T2l[o] = f2bf(ldf(W2l, idx, wf));
        T2r[o] = f2bf(ldf(W2r, idx, wf));
        Td [o] = f2bf(ldf(Wd , idx, wf));
        if (idx < NDIM) { b1c[idx] = ldf(b1l, idx, wf); b2c[idx] = ldf(b2l, idx, wf); }
    } else {
        long p = idx - NDIM * NDIM;
        long np = (long)N * 64;
        if (p < np) {
            if (wf) {
                float2 v = ((const float2*)x)[p];
                xb[p] = packbf(v.x, v.y);
            } else {
                xb[p] = ((const unsigned*)x)[p];
            }
        }
    }
}

// ---- CSR construction ------------------------------------------------------

__global__ void degree_kernel(const int* __restrict__ xedge, int E,
                              const int* __restrict__ flags, int* __restrict__ cnt) {
    int e = blockIdx.x * blockDim.x + threadIdx.x;
    if (e >= E) return;
    int d = flags[0] ? xedge[2 * (E + e)] : xedge[E + e];
    atomicAdd(&cnt[d], 1);
}

__global__ void scan_partial(const int* __restrict__ cnt, int* __restrict__ bsum, int N) {
    __shared__ int red[256];
    const int t = threadIdx.x;
    const long base = (long)blockIdx.x * SCAN_CHUNK + (long)t * 4;
    int s = 0;
#pragma unroll
    for (int i = 0; i < 4; ++i) { long idx = base + i; if (idx < N) s += cnt[idx]; }
    red[t] = s;
    __syncthreads();
    for (int off = 128; off >= 1; off >>= 1) {
        if (t < off) red[t] += red[t + off];
        __syncthreads();
    }
    if (t == 0) bsum[blockIdx.x] = red[0];
}

__global__ void scan_bsums(const int* __restrict__ bsum, int* __restrict__ boff,
                           int B, int* __restrict__ rowptr, int N) {
    __shared__ int part[1024];
    const int t = threadIdx.x;
    int v = (t < B) ? bsum[t] : 0;
    part[t] = v;
    __syncthreads();
    for (int off = 1; off < 1024; off <<= 1) {
        int u = (t >= off) ? part[t - off] : 0;
        __syncthreads();
        part[t] += u;
        __syncthreads();
    }
    if (t < B) boff[t] = part[t] - v;
    if (t == 1023) rowptr[N] = part[1023];
}

__global__ void scan_scatter(int* __restrict__ cnt, const int* __restrict__ boff,
                             int* __restrict__ rowptr, int N) {
    __shared__ int tsum[256];
    const int t = threadIdx.x;
    const long base = (long)blockIdx.x * SCAN_CHUNK + (long)t * 4;
    int loc[4];
    int s = 0;
#pragma unroll
    for (int i = 0; i < 4; ++i) {
        long idx = base + i;
        int c = (idx < N) ? cnt[idx] : 0;
        loc[i] = s;
        s += c;
    }
    tsum[t] = s;
    __syncthreads();
    for (int off = 1; off < 256; off <<= 1) {
        int u = (t >= off) ? tsum[t - off] : 0;
        __syncthreads();
        tsum[t] += u;
        __syncthreads();
    }
    const int texcl = tsum[t] - s;
    const int b0 = boff[blockIdx.x];
#pragma unroll
    for (int i = 0; i < 4; ++i) {
        long idx = base + i;
        if (idx < N) { rowptr[idx] = b0 + texcl + loc[i]; cnt[idx] = 0; }
    }
}

__global__ void fill_kernel(const int* __restrict__ xedge, int E,
                            const int* __restrict__ flags, const int* __restrict__ rowptr,
                            int* __restrict__ cur, int* __restrict__ col) {
    int e = blockIdx.x * blockDim.x + threadIdx.x;
    if (e >= E) return;
    const int e64 = flags[0];
    int s = e64 ? xedge[2 * e] : xedge[e];
    int d = e64 ? xedge[2 * (E + e)] : xedge[E + e];
    int p = rowptr[d] + atomicAdd(&cur[d], 1);
    col[p] = s;
}

// ---- SAGE layer: K-quarter-phased gather -> LDS -> MFMA dual-GEMM ----------
// OUTMODE 0: bf16 out (hbuf), LDS-staged coalesced store.
// OUTMODE 1: fused emb store (flag dtype at d_out+1elem) + decoder + BCE loss.
// Dynamic LDS: [Ms 8KB][Ss 8KB] (+ OUTMODE1: [Abf 8KB][ylds 128B][red 32B])

template <bool RELU, int OUTMODE>
__global__ __launch_bounds__(256)
void layer_mfma(const unsigned* __restrict__ Xb, const int* __restrict__ rowptr,
                const int* __restrict__ col, const short* __restrict__ WlT,
                const float* __restrict__ biasc, const short* __restrict__ WrT,
                const short* __restrict__ WdT, const void* __restrict__ yv,
                const int* __restrict__ flags, void* __restrict__ outp,
                float* __restrict__ accum, int* __restrict__ npos, int N) {
    extern __shared__ char smem[];
    short* Ms = (short*)smem;
    short* Ss = Ms + 32 * NDIM;
    unsigned* Msw = (unsigned*)Ms;
    unsigned* Ssw = (unsigned*)Ss;
    const int t = threadIdx.x;
    const int n0 = blockIdx.x * 32;
    const int wf = flags[2];

    // ---- gather: quarter-phased for L2 locality ----
    {
        const int g = t >> 6;       // row-group (wave) 0..3
        const int lane = t & 63;
        const int eo = lane >> 4;   // edge-offset group 0..3
        const int j = lane & 15;    // uint within 64B quarter
        int bk[8], ek[8];
#pragma unroll
        for (int k = 0; k < 8; ++k) {
            int n = n0 + g + 4 * k;
            int b = 0, e = 0;
            if (n < N) { b = rowptr[n]; e = rowptr[n + 1]; }
            bk[k] = b; ek[k] = e;
        }
        // self rows, full width
#pragma unroll
        for (int k = 0; k < 8; ++k) {
            int r = g + 4 * k;
            int n = n0 + r;
            unsigned su = (n < N) ? Xb[(long)n * 64 + lane] : 0u;
            Ssw[wswz(r, lane)] = su;
        }
        // quarters outermost: phase q touches only a 3.2MB slice of Xb
        for (int q = 0; q < 4; ++q) {
            const int qo = q * 16;
#pragma unroll
            for (int k = 0; k < 8; ++k) {
                const int r = g + 4 * k;
                const int b = bk[k], e = ek[k];
                float m0 = 0.f, m1 = 0.f;
                int i = b;
                for (; i + 16 <= e; i += 16) {
                    int c0 = col[i + eo], c1 = col[i + 4 + eo];
                    int c2 = col[i + 8 + eo], c3 = col[i + 12 + eo];
                    unsigned u0 = Xb[(long)c0 * 64 + qo + j];
                    unsigned u1 = Xb[(long)c1 * 64 + qo + j];
                    unsigned u2 = Xb[(long)c2 * 64 + qo + j];
                    unsigned u3 = Xb[(long)c3 * 64 + qo + j];
                    m0 += (bflo(u0) + bflo(u1)) + (bflo(u2) + bflo(u3));
                    m1 += (bfhi(u0) + bfhi(u1)) + (bfhi(u2) + bfhi(u3));
                }
                for (; i + 8 <= e; i += 8) {
                    int c0 = col[i + eo], c1 = col[i + 4 + eo];
                    unsigned u0 = Xb[(long)c0 * 64 + qo + j];
                    unsigned u1 = Xb[(long)c1 * 64 + qo + j];
                    m0 += bflo(u0) + bflo(u1);
                    m1 += bfhi(u0) + bfhi(u1);
                }
                if (i + eo < e) {
                    unsigned u = Xb[(long)col[i + eo] * 64 + qo + j];
                    m0 += bflo(u); m1 += bfhi(u);
                }
                if (i + 4 + eo < e) {
                    unsigned u = Xb[(long)col[i + 4 + eo] * 64 + qo + j];
                    m0 += bflo(u); m1 += bfhi(u);
                }
                // reduce over the 4 edge-offset groups
                m0 += __shfl_xor(m0, 16, 64);
                m0 += __shfl_xor(m0, 32, 64);
                m1 += __shfl_xor(m1, 16, 64);
                m1 += __shfl_xor(m1, 32, 64);
                if (eo == 0) {
                    float inv = 1.f / fmaxf((float)(e - b), 1.f);
                    Msw[wswz(r, qo + j)] = packbf(m0 * inv, m1 * inv);
                }
            }
        }
    }
    __syncthreads();
    // ---- MFMA: wave w owns cols [w*32, w*32+32), 2x2 16x16x32 tiles ----
    const int l = t & 63, w = t >> 6;
    const int quad = l >> 4, l15 = l & 15;
    const int wcol = w * 32;
    f32x4 acc[2][2] = {};
    for (int k0 = 0; k0 < NDIM; k0 += 32) {
        const int kc = k0 + quad * 8;
        short8 ams[2], ass[2], bl[2], br[2];
#pragma unroll
        for (int rt = 0; rt < 2; ++rt) {
            int m = rt * 16 + l15;
            ams[rt] = *(const short8*)&Ms[aswz(m, kc)];
            ass[rt] = *(const short8*)&Ss[aswz(m, kc)];
        }
#pragma unroll
        for (int ct = 0; ct < 2; ++ct) {
            int n = wcol + ct * 16 + l15;
            bl[ct] = *(const short8*)&WlT[n * NDIM + kc];
            br[ct] = *(const short8*)&WrT[n * NDIM + kc];
        }
#pragma unroll
        for (int rt = 0; rt < 2; ++rt)
#pragma unroll
            for (int ct = 0; ct < 2; ++ct) {
                acc[rt][ct] = __builtin_amdgcn_mfma_f32_16x16x32_bf16(
                    ams[rt], bl[ct], acc[rt][ct], 0, 0, 0);
                acc[rt][ct] = __builtin_amdgcn_mfma_f32_16x16x32_bf16(
                    ass[rt], br[ct], acc[rt][ct], 0, 0, 0);
            }
    }
    __syncthreads();  // all LDS reads done; reuse regions for epilogue

    if (OUTMODE == 0) {
        // stage bf16 out tile row-major in Ms region, then coalesced store
#pragma unroll
        for (int ct = 0; ct < 2; ++ct) {
            int cg = wcol + ct * 16 + l15;
            float bv = biasc[cg];
#pragma unroll
            for (int rt = 0; rt < 2; ++rt)
#pragma unroll
                for (int reg = 0; reg < 4; ++reg) {
                    int row = rt * 16 + quad * 4 + reg;
                    float v = acc[rt][ct][reg] + bv;
                    if (RELU) v = fmaxf(v, 0.f);
                    Ms[row * NDIM + cg] = f2bf(v);
                }
        }
        __syncthreads();
        unsigned* ob = (unsigned*)outp;
        for (int idx = t; idx < 2048; idx += 256) {
            int r = idx >> 6;
            if (n0 + r < N) ob[(long)n0 * 64 + idx] = Msw[idx];
        }
    } else {
        // fused emb store + decoder GEMM + BCE loss
        float* Tf  = (float*)smem;                    // 16KB fp32 emb tile
        short* Abf = (short*)(smem + 16384);          // 8KB bf16 A-tile (aswz)
        int* ylds  = (int*)(smem + 16384 + 8192);
        float* redm = (float*)(smem + 16384 + 8192 + 128);
        const int yb = flags[1];
#pragma unroll
        for (int ct = 0; ct < 2; ++ct) {
            int cg = wcol + ct * 16 + l15;
            float bv = biasc[cg];
#pragma unroll
            for (int rt = 0; rt < 2; ++rt)
#pragma unroll
                for (int reg = 0; reg < 4; ++reg) {
                    int row = rt * 16 + quad * 4 + reg;
                    float v = acc[rt][ct][reg] + bv;
                    Tf[row * NDIM + cg] = v;
                    Abf[aswz(row, cg)] = f2bf(v);
                }
        }
        if (t < 32) {
            int n = n0 + t;
            int yn = -1;
            if (n < N)
                yn = yb ? (int)((const unsigned char*)yv)[n]
                        : (((const int*)yv)[n] != 0 ? 1 : 0);
            ylds[t] = yn;
        }
        __syncthreads();
        // coalesced emb store (emb region = d_out + 1 element)
        if (wf) {
            float* embf = (float*)outp + 1;
            for (int idx = t; idx < 4096; idx += 256) {
                int r = idx >> 7;
                if (n0 + r < N) embf[(long)n0 * NDIM + idx] = Tf[idx];
            }
        } else {
            __hip_bfloat16* embh = (__hip_bfloat16*)outp + 1;
            for (int idx = t; idx < 4096; idx += 256) {
                int r = idx >> 7;
                if (n0 + r < N) embh[(long)n0 * NDIM + idx] = __float2bfloat16(Tf[idx]);
            }
        }
        // decoder GEMM from Abf
        f32x4 acc2[2][2] = {};
        for (int k0 = 0; k0 < NDIM; k0 += 32) {
            const int kc = k0 + quad * 8;
            short8 a[2], b[2];
#pragma unroll
            for (int rt = 0; rt < 2; ++rt)
                a[rt] = *(const short8*)&Abf[aswz(rt * 16 + l15, kc)];
#pragma unroll
            for (int ct = 0; ct < 2; ++ct)
                b[ct] = *(const short8*)&WdT[(wcol + ct * 16 + l15) * NDIM + kc];
#pragma unroll
            for (int rt = 0; rt < 2; ++rt)
#pragma unroll
                for (int ct = 0; ct < 2; ++ct)
                    acc2[rt][ct] = __builtin_amdgcn_mfma_f32_16x16x32_bf16(
                        a[rt], b[ct], acc2[rt][ct], 0, 0, 0);
        }
        float lpos = 0.f, lneg = 0.f;
#pragma unroll
        for (int rt = 0; rt < 2; ++rt)
#pragma unroll
            for (int reg = 0; reg < 4; ++reg) {
                int row = rt * 16 + quad * 4 + reg;
                int yn = ylds[row];
                if (yn >= 0) {
#pragma unroll
                    for (int ct = 0; ct < 2; ++ct) {
                        float z = acc2[rt][ct][reg];
                        float L = log1pf(expf(-fabsf(z)));
                        if (yn) lpos += fmaxf(-z, 0.f) + L;   // softplus(-z)
                        else    lneg += fmaxf(z, 0.f) + L;    // softplus(z)
                    }
                }
            }
#pragma unroll
        for (int off = 32; off >= 1; off >>= 1) {
            lpos += __shfl_down(lpos, off, 64);
            lneg += __shfl_down(lneg, off, 64);
        }
        if (l == 0) { redm[w * 2] = lpos; redm[w * 2 + 1] = lneg; }
        __syncthreads();
        if (t == 0) {
            atomicAdd(&accum[0], redm[0] + redm[2] + redm[4] + redm[6]);
            atomicAdd(&accum[1], redm[1] + redm[3] + redm[5] + redm[7]);
            int c = 0;
            for (int i = 0; i < 32; ++i) if (ylds[i] > 0) c++;
            if (c) atomicAdd(npos, c);
        }
    }
}

__global__ void finalize_kernel(const float* __restrict__ accum, const int* __restrict__ npos,
                                const int* __restrict__ flags, void* __restrict__ out, int N) {
    float np_ = (float)(*npos);
    float nn_ = (float)N - np_;
    float l2 = accum[0] / (fmaxf(np_, 1.f) * 128.f);
    float l1 = accum[1] / (fmaxf(nn_, 1.f) * 128.f);
    stf(out, 0, flags[2], l1 + l2);
}

// ---- launch ----------------------------------------------------------------

extern "C" void kernel_launch(void* const* d_in, const int* in_sizes, int n_in,
                              void* d_out, int out_size, void* d_ws, size_t ws_size,
                              hipStream_t stream) {
    const void* x    = d_in[0];
    const int* xedge = (const int*)d_in[1];
    const void* y    = d_in[2];
    const void* W1l  = d_in[4];
    const void* b1l  = d_in[5];
    const void* W1r  = d_in[6];
    const void* W2l  = d_in[7];
    const void* b2l  = d_in[8];
    const void* W2r  = d_in[9];
    const void* Wdec = d_in[10];

    const int N = in_sizes[0] / NDIM;
    const int E = in_sizes[1] / 2;

    char* ws = (char*)d_ws;
    size_t off = 0;
    auto alloc = [&](size_t bytes) -> void* {
        void* p = ws + off;
        off = (off + bytes + 255) & ~(size_t)255;
        return p;
    };
    int*   flags  = (int*)alloc(64);
    float* accum  = (float*)alloc(64);
    int*   npos   = (int*)alloc(64);
    int*   bsum   = (int*)alloc(1024 * 4);
    int*   boff   = (int*)alloc(1024 * 4);
    int*   cnt    = (int*)alloc((size_t)N * 4);
    int*   rowptr = (int*)alloc((size_t)(N + 1) * 4);
    int*   col    = (int*)alloc((size_t)E * 4);
    unsigned* xb  = (unsigned*)alloc((size_t)N * 64 * 4);
    unsigned* hbuf = (unsigned*)alloc((size_t)N * 64 * 4);
    short* T1l = (short*)alloc(NDIM * NDIM * 2);
    short* T1r = (short*)alloc(NDIM * NDIM * 2);
    short* T2l = (short*)alloc(NDIM * NDIM * 2);
    short* T2r = (short*)alloc(NDIM * NDIM * 2);
    short* Td  = (short*)alloc(NDIM * NDIM * 2);
    float* b1c = (float*)alloc(NDIM * 4);
    float* b2c = (float*)alloc(NDIM * 4);

    const int zb = (N + 255) / 256;
    detect_kernel<<<zb, 256, 0, stream>>>(xedge, (const unsigned int*)y,
                                          (const unsigned short*)x, flags, cnt,
                                          accum, npos, N);
    const long prep_items = (long)NDIM * NDIM + (long)N * 64;
    prep_kernel<<<(int)((prep_items + 255) / 256), 256, 0, stream>>>(
        x, W1l, b1l, W1r, W2l, b2l, W2r, Wdec, flags,
        T1l, T1r, T2l, T2r, Td, b1c, b2c, xb, N);

    const int eb = (E + 255) / 256;
    degree_kernel<<<eb, 256, 0, stream>>>(xedge, E, flags, cnt);

    const int sb = (N + SCAN_CHUNK - 1) / SCAN_CHUNK;
    scan_partial<<<sb, 256, 0, stream>>>(cnt, bsum, N);
    scan_bsums<<<1, 1024, 0, stream>>>(bsum, boff, sb, rowptr, N);
    scan_scatter<<<sb, 256, 0, stream>>>(cnt, boff, rowptr, N);

    fill_kernel<<<eb, 256, 0, stream>>>(xedge, E, flags, rowptr, cnt, col);

    const int nb32 = (N + 31) / 32;
    const size_t sm1 = 16384;
    const size_t sm2 = 16384 + 8192 + 128 + 32;
    layer_mfma<true, 0><<<nb32, 256, sm1, stream>>>(
        xb, rowptr, col, T1l, b1c, T1r, nullptr, nullptr, flags,
        hbuf, accum, npos, N);
    layer_mfma<false, 1><<<nb32, 256, sm2, stream>>>(
        hbuf, rowptr, col, T2l, b2c, T2r, Td, y, flags,
        d_out, accum, npos, N);
    finalize_kernel<<<1, 1, 0, stream>>>(accum, npos, flags, d_out, N);
}

// Round 9
// 378.675 us; speedup vs baseline: 1.2067x; 1.2067x over previous
//
#include <hip/hip_runtime.h>
#include <hip/hip_bf16.h>

#define NDIM 128
#define SCAN_CHUNK 1024  // per block: 256 threads x 4 elements

typedef __attribute__((ext_vector_type(8))) short short8;
typedef __attribute__((ext_vector_type(4))) float f32x4;

__device__ __forceinline__ float bf2f(__hip_bfloat16 v) { return __bfloat162float(v); }

__device__ __forceinline__ float ldf(const void* p, long i, int f32) {
    return f32 ? ((const float*)p)[i] : bf2f(((const __hip_bfloat16*)p)[i]);
}
__device__ __forceinline__ void stf(void* p, long i, int f32, float v) {
    if (f32) ((float*)p)[i] = v;
    else     ((__hip_bfloat16*)p)[i] = __float2bfloat16(v);
}
__device__ __forceinline__ short f2bf(float v) {
    __hip_bfloat16 h = __float2bfloat16(v);
    short s;
    __builtin_memcpy(&s, &h, 2);
    return s;
}
// bf16x2 packed in a uint: low halfword = even feature, high = odd feature
__device__ __forceinline__ float bflo(unsigned u) { u <<= 16; float f; __builtin_memcpy(&f, &u, 4); return f; }
__device__ __forceinline__ float bfhi(unsigned u) { u &= 0xffff0000u; float f; __builtin_memcpy(&f, &u, 4); return f; }
__device__ __forceinline__ unsigned packbf(float a, float b) {
    unsigned la = (unsigned short)f2bf(a);
    unsigned hb = (unsigned short)f2bf(b);
    return (hb << 16) | la;
}
// Swizzled LDS index (shorts) for A-tiles: 16B-chunk XOR by (row&7).
__device__ __forceinline__ int aswz(int m, int k) {
    return m * NDIM + ((((k >> 3) ^ (m & 7)) << 3) | (k & 7));
}
// Same swizzle at uint (bf16x2) granularity: p = feature-pair index 0..63.
__device__ __forceinline__ int wswz(int m, int p) {
    return m * 64 + ((((p >> 2) ^ (m & 7)) << 2) | (p & 3));
}

// ---- detect dtypes + zero cnt/accum/npos -----------------------------------
__global__ void detect_kernel(const int* __restrict__ xedge32,
                              const unsigned int* __restrict__ yw,
                              const unsigned short* __restrict__ xh,
                              int* __restrict__ flags, int* __restrict__ cnt,
                              float* __restrict__ accum, int* __restrict__ npos, int N) {
    const int gid = blockIdx.x * 256 + threadIdx.x;
    for (int i = gid; i < N; i += gridDim.x * 256) cnt[i] = 0;
    if (gid == 0) { accum[0] = 0.f; accum[1] = 0.f; npos[0] = 0; }
    if (blockIdx.x == 0) {
        __shared__ int se, sy, scount;
        const int t = threadIdx.x;
        if (t == 0) { se = 1; sy = 0; scount = 0; }
        __syncthreads();
        for (int i = t; i < 512; i += 256)
            if (xedge32[2 * i + 1] != 0) se = 0;
        for (int i = t; i < 1024; i += 256)
            if (yw[i] > 1u) sy = 1;
        int c = 0;
        for (int i = t; i < 1024; i += 256) {
            int ex = (xh[2 * i] >> 7) & 0xFF;
            if (ex >= 100 && ex <= 150) c++;
        }
        atomicAdd(&scount, c);
        __syncthreads();
        if (t == 0) { flags[0] = se; flags[1] = sy; flags[2] = (scount < 900) ? 1 : 0; }
    }
}

// ---- prep: weights + biases + canonical bf16x2 x + FUSED degree pass -------

__global__ void prep_kernel(const void* __restrict__ x,
                            const void* __restrict__ W1l, const void* __restrict__ b1l,
                            const void* __restrict__ W1r, const void* __restrict__ W2l,
                            const void* __restrict__ b2l, const void* __restrict__ W2r,
                            const void* __restrict__ Wd, const int* __restrict__ flags,
                            short* __restrict__ T1l, short* __restrict__ T1r,
                            short* __restrict__ T2l, short* __restrict__ T2r,
                            short* __restrict__ Td, float* __restrict__ b1c,
                            float* __restrict__ b2c, unsigned* __restrict__ xb,
                            const int* __restrict__ xedge, int E,
                            int* __restrict__ cnt, int N) {
    const int wf = flags[2];
    const long idx = (long)blockIdx.x * 256 + threadIdx.x;
    // fused degree pass (first E threads)
    if (idx < E) {
        int d = flags[0] ? xedge[2 * (E + idx)] : xedge[E + idx];
        atomicAdd(&cnt[d], 1);
    }
    if (idx < NDIM * NDIM) {
        int k = (int)(idx >> 7), n = (int)(idx & 127);
        int o = n * NDIM + k;
        T1l[o] = f2bf(ldf(W1l, idx, wf));
        T1r[o] = f2bf(ldf(W1r, idx, wf));
        T2l[o] = f2bf(ldf(W2l, idx, wf));
        T2r[o] = f2bf(ldf(W2r, idx, wf));
        Td [o] = f2bf(ldf(Wd , idx, wf));
        if (idx < NDIM) { b1c[idx] = ldf(b1l, idx, wf); b2c[idx] = ldf(b2l, idx, wf); }
    } else {
        long p = idx - NDIM * NDIM;
        long np = (long)N * 64;
        if (p < np) {
            if (wf) {
                float2 v = ((const float2*)x)[p];
                xb[p] = packbf(v.x, v.y);
            } else {
                xb[p] = ((const unsigned*)x)[p];
            }
        }
    }
}

// ---- 3-phase multi-block exclusive scan of cnt -> rowptr -------------------

__global__ void scan_partial(const int* __restrict__ cnt, int* __restrict__ bsum, int N) {
    __shared__ int red[256];
    const int t = threadIdx.x;
    const long base = (long)blockIdx.x * SCAN_CHUNK + (long)t * 4;
    int s = 0;
#pragma unroll
    for (int i = 0; i < 4; ++i) { long idx = base + i; if (idx < N) s += cnt[idx]; }
    red[t] = s;
    __syncthreads();
    for (int off = 128; off >= 1; off >>= 1) {
        if (t < off) red[t] += red[t + off];
        __syncthreads();
    }
    if (t == 0) bsum[blockIdx.x] = red[0];
}

__global__ void scan_bsums(const int* __restrict__ bsum, int* __restrict__ boff,
                           int B, int* __restrict__ rowptr, int N) {
    __shared__ int part[1024];
    const int t = threadIdx.x;
    int v = (t < B) ? bsum[t] : 0;
    part[t] = v;
    __syncthreads();
    for (int off = 1; off < 1024; off <<= 1) {
        int u = (t >= off) ? part[t - off] : 0;
        __syncthreads();
        part[t] += u;
        __syncthreads();
    }
    if (t < B) boff[t] = part[t] - v;
    if (t == 1023) rowptr[N] = part[1023];
}

__global__ void scan_scatter(int* __restrict__ cnt, const int* __restrict__ boff,
                             int* __restrict__ rowptr, int N) {
    __shared__ int tsum[256];
    const int t = threadIdx.x;
    const long base = (long)blockIdx.x * SCAN_CHUNK + (long)t * 4;
    int loc[4];
    int s = 0;
#pragma unroll
    for (int i = 0; i < 4; ++i) {
        long idx = base + i;
        int c = (idx < N) ? cnt[idx] : 0;
        loc[i] = s;
        s += c;
    }
    tsum[t] = s;
    __syncthreads();
    for (int off = 1; off < 256; off <<= 1) {
        int u = (t >= off) ? tsum[t - off] : 0;
        __syncthreads();
        tsum[t] += u;
        __syncthreads();
    }
    const int texcl = tsum[t] - s;
    const int b0 = boff[blockIdx.x];
#pragma unroll
    for (int i = 0; i < 4; ++i) {
        long idx = base + i;
        if (idx < N) { rowptr[idx] = b0 + texcl + loc[i]; cnt[idx] = 0; }
    }
}

__global__ void fill_kernel(const int* __restrict__ xedge, int E,
                            const int* __restrict__ flags, const int* __restrict__ rowptr,
                            int* __restrict__ cur, int* __restrict__ col) {
    int e = blockIdx.x * blockDim.x + threadIdx.x;
    if (e >= E) return;
    const int e64 = flags[0];
    int s = e64 ? xedge[2 * e] : xedge[e];
    int d = e64 ? xedge[2 * (E + e)] : xedge[E + e];
    int p = rowptr[d] + atomicAdd(&cur[d], 1);
    col[p] = s;
}

// ---- SAGE layer: unrolled bf16x2 gather-mean -> LDS -> MFMA dual-GEMM ------
// OUTMODE 0: bf16 out (outp=hbuf), LDS-staged coalesced store.
// OUTMODE 1: emb out (flag dtype at d_out+1elem) + bf16 copy into hemb.
// NOTE: hemb must NOT alias the gather input Xb (inter-block race) — caller
// passes xb (dead after layer 1).

template <bool RELU, int OUTMODE>
__global__ __launch_bounds__(256)
void layer_mfma(const unsigned* __restrict__ Xb, const int* __restrict__ rowptr,
                const int* __restrict__ col, const short* __restrict__ WlT,
                const float* __restrict__ biasc, const short* __restrict__ WrT,
                const int* __restrict__ flags, void* __restrict__ outp,
                unsigned* __restrict__ hemb, int N) {
    __shared__ short AS[2 * 32 * NDIM];  // [Ms 8KB][Ss 8KB], contiguous
    short* Ms = AS;
    short* Ss = AS + 32 * NDIM;
    unsigned* Msw = (unsigned*)Ms;
    unsigned* Ssw = (unsigned*)Ss;
    const int t = threadIdx.x;
    const int n0 = blockIdx.x * 32;
    const int wf = flags[2];
    // ---- gather: 4 row-groups of 64 lanes; lane = feature-pair; unroll 8 ----
    {
        const int g = t >> 6, p = t & 63;
        for (int r = g; r < 32; r += 4) {
            int n = n0 + r;
            float m0 = 0.f, m1 = 0.f;
            unsigned su = 0;
            if (n < N) {
                int b = rowptr[n], e = rowptr[n + 1];
                int i = b;
                for (; i + 8 <= e; i += 8) {
                    unsigned u0 = Xb[(long)col[i    ] * 64 + p];
                    unsigned u1 = Xb[(long)col[i + 1] * 64 + p];
                    unsigned u2 = Xb[(long)col[i + 2] * 64 + p];
                    unsigned u3 = Xb[(long)col[i + 3] * 64 + p];
                    unsigned u4 = Xb[(long)col[i + 4] * 64 + p];
                    unsigned u5 = Xb[(long)col[i + 5] * 64 + p];
                    unsigned u6 = Xb[(long)col[i + 6] * 64 + p];
                    unsigned u7 = Xb[(long)col[i + 7] * 64 + p];
                    m0 += ((bflo(u0) + bflo(u1)) + (bflo(u2) + bflo(u3)))
                        + ((bflo(u4) + bflo(u5)) + (bflo(u6) + bflo(u7)));
                    m1 += ((bfhi(u0) + bfhi(u1)) + (bfhi(u2) + bfhi(u3)))
                        + ((bfhi(u4) + bfhi(u5)) + (bfhi(u6) + bfhi(u7)));
                }
                for (; i < e; ++i) {
                    unsigned u = Xb[(long)col[i] * 64 + p];
                    m0 += bflo(u);
                    m1 += bfhi(u);
                }
                float inv = 1.f / fmaxf((float)(e - b), 1.f);
                m0 *= inv; m1 *= inv;
                su = Xb[(long)n * 64 + p];
            }
            int wi = wswz(r, p);
            Msw[wi] = packbf(m0, m1);
            Ssw[wi] = su;
        }
    }
    __syncthreads();
    // ---- MFMA: wave w owns cols [w*32, w*32+32), 2x2 16x16x32 tiles ----
    const int l = t & 63, w = t >> 6;
    const int quad = l >> 4, l15 = l & 15;
    const int wcol = w * 32;
    f32x4 acc[2][2] = {};
    for (int k0 = 0; k0 < NDIM; k0 += 32) {
        const int kc = k0 + quad * 8;
        short8 ams[2], ass[2], bl[2], br[2];
#pragma unroll
        for (int rt = 0; rt < 2; ++rt) {
            int m = rt * 16 + l15;
            ams[rt] = *(const short8*)&Ms[aswz(m, kc)];
            ass[rt] = *(const short8*)&Ss[aswz(m, kc)];
        }
#pragma unroll
        for (int ct = 0; ct < 2; ++ct) {
            int n = wcol + ct * 16 + l15;
            bl[ct] = *(const short8*)&WlT[n * NDIM + kc];
            br[ct] = *(const short8*)&WrT[n * NDIM + kc];
        }
#pragma unroll
        for (int rt = 0; rt < 2; ++rt)
#pragma unroll
            for (int ct = 0; ct < 2; ++ct) {
                acc[rt][ct] = __builtin_amdgcn_mfma_f32_16x16x32_bf16(
                    ams[rt], bl[ct], acc[rt][ct], 0, 0, 0);
                acc[rt][ct] = __builtin_amdgcn_mfma_f32_16x16x32_bf16(
                    ass[rt], br[ct], acc[rt][ct], 0, 0, 0);
            }
    }
    __syncthreads();  // all MFMA LDS reads done; reuse AS for epilogue staging

    if (OUTMODE == 0) {
        // bf16 out tile row-major in Ms region, then coalesced uint store
#pragma unroll
        for (int ct = 0; ct < 2; ++ct) {
            int cg = wcol + ct * 16 + l15;
            float bv = biasc[cg];
#pragma unroll
            for (int rt = 0; rt < 2; ++rt)
#pragma unroll
                for (int reg = 0; reg < 4; ++reg) {
                    int row = rt * 16 + quad * 4 + reg;
                    float v = acc[rt][ct][reg] + bv;
                    if (RELU) v = fmaxf(v, 0.f);
                    Ms[row * NDIM + cg] = f2bf(v);
                }
        }
        __syncthreads();
        unsigned* ob = (unsigned*)outp;
        for (int idx = t; idx < 2048; idx += 256) {
            int r = idx >> 6;
            if (n0 + r < N) ob[(long)n0 * 64 + idx] = Msw[idx];
        }
    } else {
        // ---- Pass A (fp32 emb store, only if out dtype is fp32) ----
        if (wf) {
            float* Tf = (float*)AS;  // full 16KB = 32x128 fp32
#pragma unroll
            for (int ct = 0; ct < 2; ++ct) {
                int cg = wcol + ct * 16 + l15;
                float bv = biasc[cg];
#pragma unroll
                for (int rt = 0; rt < 2; ++rt)
#pragma unroll
                    for (int reg = 0; reg < 4; ++reg) {
                        int row = rt * 16 + quad * 4 + reg;
                        Tf[row * NDIM + cg] = acc[rt][ct][reg] + bv;
                    }
            }
            __syncthreads();
            float* embf = (float*)outp + 1;
            for (int idx = t; idx < 4096; idx += 256) {
                int r = idx >> 7;
                if (n0 + r < N) embf[(long)n0 * NDIM + idx] = Tf[idx];
            }
            __syncthreads();
        }
        // ---- Pass B: bf16 row-major tile -> hemb (+ emb region if bf16) ----
#pragma unroll
        for (int ct = 0; ct < 2; ++ct) {
            int cg = wcol + ct * 16 + l15;
            float bv = biasc[cg];
#pragma unroll
            for (int rt = 0; rt < 2; ++rt)
#pragma unroll
                for (int reg = 0; reg < 4; ++reg) {
                    int row = rt * 16 + quad * 4 + reg;
                    Ms[row * NDIM + cg] = f2bf(acc[rt][ct][reg] + bv);
                }
        }
        __syncthreads();
        for (int idx = t; idx < 2048; idx += 256) {
            int r = idx >> 6;
            if (n0 + r < N) hemb[(long)n0 * 64 + idx] = Msw[idx];
        }
        if (!wf) {
            short* embh = (short*)outp + 1;  // bf16 emb region (2B aligned)
            for (int idx = t; idx < 4096; idx += 256) {
                int r = idx >> 7;
                if (n0 + r < N) embh[(long)n0 * NDIM + idx] = Ms[idx];
            }
        }
    }
}

// ---- decoder GEMM + BCE-with-logits, MFMA; reads bf16x2 hemb ---------------

__global__ __launch_bounds__(256)
void loss_mfma(const unsigned* __restrict__ hemb, const short* __restrict__ WdT,
               const void* __restrict__ yv, const int* __restrict__ flags,
               float* __restrict__ accum, int* __restrict__ npos, int N) {
    __shared__ short As[32 * NDIM];
    __shared__ int ylds[32];
    __shared__ float red[4][2];
    unsigned* Asw = (unsigned*)As;
    const int t = threadIdx.x;
    const int n0 = blockIdx.x * 32;
    const int yb = flags[1];
    {
        const int g = t >> 6, p = t & 63;
        for (int r = g; r < 32; r += 4) {
            int n = n0 + r;
            Asw[wswz(r, p)] = (n < N) ? hemb[(long)n * 64 + p] : 0u;
        }
        if (t < 32) {
            int n = n0 + t;
            int yn = -1;
            if (n < N)
                yn = yb ? (int)((const unsigned char*)yv)[n]
                        : (((const int*)yv)[n] != 0 ? 1 : 0);
            ylds[t] = yn;
        }
    }
    __syncthreads();
    const int l = t & 63, w = t >> 6;
    const int quad = l >> 4, l15 = l & 15;
    const int wcol = w * 32;
    f32x4 acc[2][2] = {};
    for (int k0 = 0; k0 < NDIM; k0 += 32) {
        const int kc = k0 + quad * 8;
        short8 a[2], b[2];
#pragma unroll
        for (int rt = 0; rt < 2; ++rt)
            a[rt] = *(const short8*)&As[aswz(rt * 16 + l15, kc)];
#pragma unroll
        for (int ct = 0; ct < 2; ++ct)
            b[ct] = *(const short8*)&WdT[(wcol + ct * 16 + l15) * NDIM + kc];
#pragma unroll
        for (int rt = 0; rt < 2; ++rt)
#pragma unroll
            for (int ct = 0; ct < 2; ++ct)
                acc[rt][ct] = __builtin_amdgcn_mfma_f32_16x16x32_bf16(
                    a[rt], b[ct], acc[rt][ct], 0, 0, 0);
    }
    float lpos = 0.f, lneg = 0.f;
#pragma unroll
    for (int rt = 0; rt < 2; ++rt)
#pragma unroll
        for (int reg = 0; reg < 4; ++reg) {
            int row = rt * 16 + quad * 4 + reg;
            int yn = ylds[row];
            if (yn >= 0) {
#pragma unroll
                for (int ct = 0; ct < 2; ++ct) {
                    float z = acc[rt][ct][reg];
                    float L = log1pf(expf(-fabsf(z)));
                    if (yn) lpos += fmaxf(-z, 0.f) + L;   // softplus(-z)
                    else    lneg += fmaxf(z, 0.f) + L;    // softplus(z)
                }
            }
        }
#pragma unroll
    for (int off = 32; off >= 1; off >>= 1) {
        lpos += __shfl_down(lpos, off, 64);
        lneg += __shfl_down(lneg, off, 64);
    }
    if (l == 0) { red[w][0] = lpos; red[w][1] = lneg; }
    __syncthreads();
    if (t == 0) {
        atomicAdd(&accum[0], red[0][0] + red[1][0] + red[2][0] + red[3][0]);
        atomicAdd(&accum[1], red[0][1] + red[1][1] + red[2][1] + red[3][1]);
        int c = 0;
        for (int i = 0; i < 32; ++i) if (ylds[i] > 0) c++;
        if (c) atomicAdd(npos, c);
    }
}

__global__ void finalize_kernel(const float* __restrict__ accum, const int* __restrict__ npos,
                                const int* __restrict__ flags, void* __restrict__ out, int N) {
    float np_ = (float)(*npos);
    float nn_ = (float)N - np_;
    float l2 = accum[0] / (fmaxf(np_, 1.f) * 128.f);
    float l1 = accum[1] / (fmaxf(nn_, 1.f) * 128.f);
    stf(out, 0, flags[2], l1 + l2);
}

// ---- launch ----------------------------------------------------------------

extern "C" void kernel_launch(void* const* d_in, const int* in_sizes, int n_in,
                              void* d_out, int out_size, void* d_ws, size_t ws_size,
                              hipStream_t stream) {
    const void* x    = d_in[0];
    const int* xedge = (const int*)d_in[1];
    const void* y    = d_in[2];
    const void* W1l  = d_in[4];
    const void* b1l  = d_in[5];
    const void* W1r  = d_in[6];
    const void* W2l  = d_in[7];
    const void* b2l  = d_in[8];
    const void* W2r  = d_in[9];
    const void* Wdec = d_in[10];

    const int N = in_sizes[0] / NDIM;
    const int E = in_sizes[1] / 2;

    char* ws = (char*)d_ws;
    size_t off = 0;
    auto alloc = [&](size_t bytes) -> void* {
        void* p = ws + off;
        off = (off + bytes + 255) & ~(size_t)255;
        return p;
    };
    int*   flags  = (int*)alloc(64);
    float* accum  = (float*)alloc(64);
    int*   npos   = (int*)alloc(64);
    int*   bsum   = (int*)alloc(1024 * 4);
    int*   boff   = (int*)alloc(1024 * 4);
    int*   cnt    = (int*)alloc((size_t)N * 4);
    int*   rowptr = (int*)alloc((size_t)(N + 1) * 4);
    int*   col    = (int*)alloc((size_t)E * 4);
    unsigned* xb  = (unsigned*)alloc((size_t)N * 64 * 4);   // x, then bf16 emb
    unsigned* hbuf = (unsigned*)alloc((size_t)N * 64 * 4);  // h (layer-1 out)
    short* T1l = (short*)alloc(NDIM * NDIM * 2);
    short* T1r = (short*)alloc(NDIM * NDIM * 2);
    short* T2l = (short*)alloc(NDIM * NDIM * 2);
    short* T2r = (short*)alloc(NDIM * NDIM * 2);
    short* Td  = (short*)alloc(NDIM * NDIM * 2);
    float* b1c = (float*)alloc(NDIM * 4);
    float* b2c = (float*)alloc(NDIM * 4);

    const int zb = (N + 255) / 256;
    detect_kernel<<<zb, 256, 0, stream>>>(xedge, (const unsigned int*)y,
                                          (const unsigned short*)x, flags, cnt,
                                          accum, npos, N);
    const long prep_items = (long)NDIM * NDIM + (long)N * 64;  // >> E
    prep_kernel<<<(int)((prep_items + 255) / 256), 256, 0, stream>>>(
        x, W1l, b1l, W1r, W2l, b2l, W2r, Wdec, flags,
        T1l, T1r, T2l, T2r, Td, b1c, b2c, xb, xedge, E, cnt, N);

    const int sb = (N + SCAN_CHUNK - 1) / SCAN_CHUNK;
    scan_partial<<<sb, 256, 0, stream>>>(cnt, bsum, N);
    scan_bsums<<<1, 1024, 0, stream>>>(bsum, boff, sb, rowptr, N);
    scan_scatter<<<sb, 256, 0, stream>>>(cnt, boff, rowptr, N);

    const int eb = (E + 255) / 256;
    fill_kernel<<<eb, 256, 0, stream>>>(xedge, E, flags, rowptr, cnt, col);

    const int nb32 = (N + 31) / 32;
    // layer 1: reads xb, writes hbuf
    layer_mfma<true, 0><<<nb32, 256, 0, stream>>>(
        xb, rowptr, col, T1l, b1c, T1r, flags, hbuf, nullptr, N);
    // layer 2: reads hbuf, writes d_out emb + bf16 emb into xb (xb is dead;
    // must NOT alias hbuf -> round-8 race)
    layer_mfma<false, 1><<<nb32, 256, 0, stream>>>(
        hbuf, rowptr, col, T2l, b2c, T2r, flags, d_out, xb, N);
    loss_mfma<<<nb32, 256, 0, stream>>>(xb, Td, y, flags, accum, npos, N);
    finalize_kernel<<<1, 1, 0, stream>>>(accum, npos, flags, d_out, N);
}

// Round 10
// 369.499 us; speedup vs baseline: 1.2367x; 1.0248x over previous
//
#include <hip/hip_runtime.h>
#include <hip/hip_bf16.h>

#define NDIM 128
#define SCAN_CHUNK 1024  // per block: 256 threads x 4 elements

typedef __attribute__((ext_vector_type(8))) short short8;
typedef __attribute__((ext_vector_type(4))) float f32x4;

__device__ __forceinline__ float bf2f(__hip_bfloat16 v) { return __bfloat162float(v); }

__device__ __forceinline__ float ldf(const void* p, long i, int f32) {
    return f32 ? ((const float*)p)[i] : bf2f(((const __hip_bfloat16*)p)[i]);
}
__device__ __forceinline__ void stf(void* p, long i, int f32, float v) {
    if (f32) ((float*)p)[i] = v;
    else     ((__hip_bfloat16*)p)[i] = __float2bfloat16(v);
}
__device__ __forceinline__ short f2bf(float v) {
    __hip_bfloat16 h = __float2bfloat16(v);
    short s;
    __builtin_memcpy(&s, &h, 2);
    return s;
}
// bf16x2 packed in a uint: low halfword = even feature, high = odd feature
__device__ __forceinline__ float bflo(unsigned u) { u <<= 16; float f; __builtin_memcpy(&f, &u, 4); return f; }
__device__ __forceinline__ float bfhi(unsigned u) { u &= 0xffff0000u; float f; __builtin_memcpy(&f, &u, 4); return f; }
__device__ __forceinline__ unsigned packbf(float a, float b) {
    unsigned la = (unsigned short)f2bf(a);
    unsigned hb = (unsigned short)f2bf(b);
    return (hb << 16) | la;
}
// Swizzled LDS index (shorts) for A-tiles: 16B-chunk XOR by (row&7).
__device__ __forceinline__ int aswz(int m, int k) {
    return m * NDIM + ((((k >> 3) ^ (m & 7)) << 3) | (k & 7));
}
// Same swizzle at uint (bf16x2) granularity: p = feature-pair index 0..63.
__device__ __forceinline__ int wswz(int m, int p) {
    return m * 64 + ((((p >> 2) ^ (m & 7)) << 2) | (p & 3));
}

// ---- detect dtypes + zero cnt/accum/npos -----------------------------------
__global__ void detect_kernel(const int* __restrict__ xedge32,
                              const unsigned int* __restrict__ yw,
                              const unsigned short* __restrict__ xh,
                              int* __restrict__ flags, int* __restrict__ cnt,
                              float* __restrict__ accum, int* __restrict__ npos, int N) {
    const int gid = blockIdx.x * 256 + threadIdx.x;
    for (int i = gid; i < N; i += gridDim.x * 256) cnt[i] = 0;
    if (gid == 0) { accum[0] = 0.f; accum[1] = 0.f; npos[0] = 0; }
    if (blockIdx.x == 0) {
        __shared__ int se, sy, scount;
        const int t = threadIdx.x;
        if (t == 0) { se = 1; sy = 0; scount = 0; }
        __syncthreads();
        for (int i = t; i < 512; i += 256)
            if (xedge32[2 * i + 1] != 0) se = 0;
        for (int i = t; i < 1024; i += 256)
            if (yw[i] > 1u) sy = 1;
        int c = 0;
        for (int i = t; i < 1024; i += 256) {
            int ex = (xh[2 * i] >> 7) & 0xFF;
            if (ex >= 100 && ex <= 150) c++;
        }
        atomicAdd(&scount, c);
        __syncthreads();
        if (t == 0) { flags[0] = se; flags[1] = sy; flags[2] = (scount < 900) ? 1 : 0; }
    }
}

// ---- prep: weights + biases + canonical bf16x2 x + FUSED degree pass -------

__global__ void prep_kernel(const void* __restrict__ x,
                            const void* __restrict__ W1l, const void* __restrict__ b1l,
                            const void* __restrict__ W1r, const void* __restrict__ W2l,
                            const void* __restrict__ b2l, const void* __restrict__ W2r,
                            const void* __restrict__ Wd, const int* __restrict__ flags,
                            short* __restrict__ T1l, short* __restrict__ T1r,
                            short* __restrict__ T2l, short* __restrict__ T2r,
                            short* __restrict__ Td, float* __restrict__ b1c,
                            float* __restrict__ b2c, unsigned* __restrict__ xb,
                            const int* __restrict__ xedge, int E,
                            int* __restrict__ cnt, int N) {
    const int wf = flags[2];
    const long idx = (long)blockIdx.x * 256 + threadIdx.x;
    // fused degree pass (first E threads)
    if (idx < E) {
        int d = flags[0] ? xedge[2 * (E + idx)] : xedge[E + idx];
        atomicAdd(&cnt[d], 1);
    }
    if (idx < NDIM * NDIM) {
        int k = (int)(idx >> 7), n = (int)(idx & 127);
        int o = n * NDIM + k;
        T1l[o] = f2bf(ldf(W1l, idx, wf));
        T1r[o] = f2bf(ldf(W1r, idx, wf));
        T2l[o] = f2bf(ldf(W2l, idx, wf));
        T2r[o] = f2bf(ldf(W2r, idx, wf));
        Td [o] = f2bf(ldf(Wd , idx, wf));
        if (idx < NDIM) { b1c[idx] = ldf(b1l, idx, wf); b2c[idx] = ldf(b2l, idx, wf); }
    } else {
        long p = idx - NDIM * NDIM;
        long np = (long)N * 64;
        if (p < np) {
            if (wf) {
                float2 v = ((const float2*)x)[p];
                xb[p] = packbf(v.x, v.y);
            } else {
                xb[p] = ((const unsigned*)x)[p];
            }
        }
    }
}

// ---- 3-phase multi-block exclusive scan of cnt -> rowptr -------------------

__global__ void scan_partial(const int* __restrict__ cnt, int* __restrict__ bsum, int N) {
    __shared__ int red[256];
    const int t = threadIdx.x;
    const long base = (long)blockIdx.x * SCAN_CHUNK + (long)t * 4;
    int s = 0;
#pragma unroll
    for (int i = 0; i < 4; ++i) { long idx = base + i; if (idx < N) s += cnt[idx]; }
    red[t] = s;
    __syncthreads();
    for (int off = 128; off >= 1; off >>= 1) {
        if (t < off) red[t] += red[t + off];
        __syncthreads();
    }
    if (t == 0) bsum[blockIdx.x] = red[0];
}

__global__ void scan_bsums(const int* __restrict__ bsum, int* __restrict__ boff,
                           int B, int* __restrict__ rowptr, int N) {
    __shared__ int part[1024];
    const int t = threadIdx.x;
    int v = (t < B) ? bsum[t] : 0;
    part[t] = v;
    __syncthreads();
    for (int off = 1; off < 1024; off <<= 1) {
        int u = (t >= off) ? part[t - off] : 0;
        __syncthreads();
        part[t] += u;
        __syncthreads();
    }
    if (t < B) boff[t] = part[t] - v;
    if (t == 1023) rowptr[N] = part[1023];
}

__global__ void scan_scatter(int* __restrict__ cnt, const int* __restrict__ boff,
                             int* __restrict__ rowptr, int N) {
    __shared__ int tsum[256];
    const int t = threadIdx.x;
    const long base = (long)blockIdx.x * SCAN_CHUNK + (long)t * 4;
    int loc[4];
    int s = 0;
#pragma unroll
    for (int i = 0; i < 4; ++i) {
        long idx = base + i;
        int c = (idx < N) ? cnt[idx] : 0;
        loc[i] = s;
        s += c;
    }
    tsum[t] = s;
    __syncthreads();
    for (int off = 1; off < 256; off <<= 1) {
        int u = (t >= off) ? tsum[t - off] : 0;
        __syncthreads();
        tsum[t] += u;
        __syncthreads();
    }
    const int texcl = tsum[t] - s;
    const int b0 = boff[blockIdx.x];
#pragma unroll
    for (int i = 0; i < 4; ++i) {
        long idx = base + i;
        if (idx < N) { rowptr[idx] = b0 + texcl + loc[i]; cnt[idx] = 0; }
    }
}

__global__ void fill_kernel(const int* __restrict__ xedge, int E,
                            const int* __restrict__ flags, const int* __restrict__ rowptr,
                            int* __restrict__ cur, int* __restrict__ col) {
    int e = blockIdx.x * blockDim.x + threadIdx.x;
    if (e >= E) return;
    const int e64 = flags[0];
    int s = e64 ? xedge[2 * e] : xedge[e];
    int d = e64 ? xedge[2 * (E + e)] : xedge[E + e];
    int p = rowptr[d] + atomicAdd(&cur[d], 1);
    col[p] = s;
}

// ---- SAGE layer: 2-row-interleaved gather-mean -> LDS -> MFMA dual-GEMM ----
// OUTMODE 0: bf16 out (outp=hbuf), LDS-staged coalesced store.
// OUTMODE 1: FUSED: emb direct-store (flag dtype at d_out+1elem) + decoder
//            MFMA + BCE loss accumulation (round-7-verified epilogue).

template <bool RELU, int OUTMODE>
__global__ __launch_bounds__(256)
void layer_mfma(const unsigned* __restrict__ Xb, const int* __restrict__ rowptr,
                const int* __restrict__ col, const short* __restrict__ WlT,
                const float* __restrict__ biasc, const short* __restrict__ WrT,
                const short* __restrict__ WdT, const void* __restrict__ yv,
                const int* __restrict__ flags, void* __restrict__ outp,
                float* __restrict__ accum, int* __restrict__ npos, int N) {
    __shared__ short AS[2 * 32 * NDIM];  // [Ms 8KB][Ss 8KB]
    __shared__ int ylds[32];
    __shared__ float redm[4][2];
    short* Ms = AS;
    short* Ss = AS + 32 * NDIM;
    unsigned* Msw = (unsigned*)Ms;
    unsigned* Ssw = (unsigned*)Ss;
    const int t = threadIdx.x;
    const int n0 = blockIdx.x * 32;
    const int wf = flags[2];

    if (OUTMODE == 1 && t < 32) {
        const int yb = flags[1];
        int n = n0 + t;
        int yn = -1;
        if (n < N)
            yn = yb ? (int)((const unsigned char*)yv)[n]
                    : (((const int*)yv)[n] != 0 ? 1 : 0);
        ylds[t] = yn;
    }

    // ---- gather: 4 waves x 4 row-pairs; 16 gather loads in flight/lane ----
    {
        const int g = t >> 6, p = t & 63;
        for (int k = 0; k < 4; ++k) {
            const int rA = g + 8 * k, rB = rA + 4;
            const int nA = n0 + rA, nB = n0 + rB;
            float a0 = 0.f, a1 = 0.f, c0 = 0.f, c1 = 0.f;
            unsigned sA = 0u, sB = 0u;
            int bA = 0, eA = 0, bB = 0, eB = 0;
            if (nA < N) { bA = rowptr[nA]; eA = rowptr[nA + 1]; sA = Xb[(long)nA * 64 + p]; }
            if (nB < N) { bB = rowptr[nB]; eB = rowptr[nB + 1]; sB = Xb[(long)nB * 64 + p]; }
            int iA = bA, iB = bB;
            while (iA + 8 <= eA && iB + 8 <= eB) {
                unsigned uA[8], uB[8];
#pragma unroll
                for (int j = 0; j < 8; ++j) uA[j] = Xb[(long)col[iA + j] * 64 + p];
#pragma unroll
                for (int j = 0; j < 8; ++j) uB[j] = Xb[(long)col[iB + j] * 64 + p];
#pragma unroll
                for (int j = 0; j < 8; ++j) { a0 += bflo(uA[j]); a1 += bfhi(uA[j]); }
#pragma unroll
                for (int j = 0; j < 8; ++j) { c0 += bflo(uB[j]); c1 += bfhi(uB[j]); }
                iA += 8; iB += 8;
            }
            for (; iA + 8 <= eA; iA += 8) {
                unsigned u[8];
#pragma unroll
                for (int j = 0; j < 8; ++j) u[j] = Xb[(long)col[iA + j] * 64 + p];
#pragma unroll
                for (int j = 0; j < 8; ++j) { a0 += bflo(u[j]); a1 += bfhi(u[j]); }
            }
            for (; iB + 8 <= eB; iB += 8) {
                unsigned u[8];
#pragma unroll
                for (int j = 0; j < 8; ++j) u[j] = Xb[(long)col[iB + j] * 64 + p];
#pragma unroll
                for (int j = 0; j < 8; ++j) { c0 += bflo(u[j]); c1 += bfhi(u[j]); }
            }
            for (; iA < eA; ++iA) {
                unsigned u = Xb[(long)col[iA] * 64 + p];
                a0 += bflo(u); a1 += bfhi(u);
            }
            for (; iB < eB; ++iB) {
                unsigned u = Xb[(long)col[iB] * 64 + p];
                c0 += bflo(u); c1 += bfhi(u);
            }
            float invA = 1.f / fmaxf((float)(eA - bA), 1.f);
            float invB = 1.f / fmaxf((float)(eB - bB), 1.f);
            Msw[wswz(rA, p)] = packbf(a0 * invA, a1 * invA);
            Ssw[wswz(rA, p)] = sA;
            Msw[wswz(rB, p)] = packbf(c0 * invB, c1 * invB);
            Ssw[wswz(rB, p)] = sB;
        }
    }
    __syncthreads();
    // ---- MFMA: wave w owns cols [w*32, w*32+32), 2x2 16x16x32 tiles ----
    const int l = t & 63, w = t >> 6;
    const int quad = l >> 4, l15 = l & 15;
    const int wcol = w * 32;
    f32x4 acc[2][2] = {};
    for (int k0 = 0; k0 < NDIM; k0 += 32) {
        const int kc = k0 + quad * 8;
        short8 ams[2], ass[2], bl[2], br[2];
#pragma unroll
        for (int rt = 0; rt < 2; ++rt) {
            int m = rt * 16 + l15;
            ams[rt] = *(const short8*)&Ms[aswz(m, kc)];
            ass[rt] = *(const short8*)&Ss[aswz(m, kc)];
        }
#pragma unroll
        for (int ct = 0; ct < 2; ++ct) {
            int n = wcol + ct * 16 + l15;
            bl[ct] = *(const short8*)&WlT[n * NDIM + kc];
            br[ct] = *(const short8*)&WrT[n * NDIM + kc];
        }
#pragma unroll
        for (int rt = 0; rt < 2; ++rt)
#pragma unroll
            for (int ct = 0; ct < 2; ++ct) {
                acc[rt][ct] = __builtin_amdgcn_mfma_f32_16x16x32_bf16(
                    ams[rt], bl[ct], acc[rt][ct], 0, 0, 0);
                acc[rt][ct] = __builtin_amdgcn_mfma_f32_16x16x32_bf16(
                    ass[rt], br[ct], acc[rt][ct], 0, 0, 0);
            }
    }
    __syncthreads();  // all MFMA LDS reads done; Ms/Ss reusable

    if (OUTMODE == 0) {
        // bf16 out tile row-major in Ms region, then coalesced uint store
#pragma unroll
        for (int ct = 0; ct < 2; ++ct) {
            int cg = wcol + ct * 16 + l15;
            float bv = biasc[cg];
#pragma unroll
            for (int rt = 0; rt < 2; ++rt)
#pragma unroll
                for (int reg = 0; reg < 4; ++reg) {
                    int row = rt * 16 + quad * 4 + reg;
                    float v = acc[rt][ct][reg] + bv;
                    if (RELU) v = fmaxf(v, 0.f);
                    Ms[row * NDIM + cg] = f2bf(v);
                }
        }
        __syncthreads();
        unsigned* ob = (unsigned*)outp;
        for (int idx = t; idx < 2048; idx += 256) {
            int r = idx >> 6;
            if (n0 + r < N) ob[(long)n0 * 64 + idx] = Msw[idx];
        }
    } else {
        // ---- fused: Abf into Ms (aswz) + direct emb store from registers ----
#pragma unroll
        for (int ct = 0; ct < 2; ++ct) {
            int cg = wcol + ct * 16 + l15;
            float bv = biasc[cg];
#pragma unroll
            for (int rt = 0; rt < 2; ++rt)
#pragma unroll
                for (int reg = 0; reg < 4; ++reg) {
                    int row = rt * 16 + quad * 4 + reg;
                    float v = acc[rt][ct][reg] + bv;
                    Ms[aswz(row, cg)] = f2bf(v);
                    int n = n0 + row;
                    if (n < N) {
                        if (wf) ((float*)outp)[1 + (long)n * NDIM + cg] = v;
                        else ((__hip_bfloat16*)outp)[1 + (long)n * NDIM + cg] =
                                 __float2bfloat16(v);
                    }
                }
        }
        __syncthreads();
        // ---- decoder GEMM from Abf(Ms) ----
        f32x4 acc2[2][2] = {};
        for (int k0 = 0; k0 < NDIM; k0 += 32) {
            const int kc = k0 + quad * 8;
            short8 a[2], b[2];
#pragma unroll
            for (int rt = 0; rt < 2; ++rt)
                a[rt] = *(const short8*)&Ms[aswz(rt * 16 + l15, kc)];
#pragma unroll
            for (int ct = 0; ct < 2; ++ct)
                b[ct] = *(const short8*)&WdT[(wcol + ct * 16 + l15) * NDIM + kc];
#pragma unroll
            for (int rt = 0; rt < 2; ++rt)
#pragma unroll
                for (int ct = 0; ct < 2; ++ct)
                    acc2[rt][ct] = __builtin_amdgcn_mfma_f32_16x16x32_bf16(
                        a[rt], b[ct], acc2[rt][ct], 0, 0, 0);
        }
        float lpos = 0.f, lneg = 0.f;
#pragma unroll
        for (int rt = 0; rt < 2; ++rt)
#pragma unroll
            for (int reg = 0; reg < 4; ++reg) {
                int row = rt * 16 + quad * 4 + reg;
                int yn = ylds[row];
                if (yn >= 0) {
#pragma unroll
                    for (int ct = 0; ct < 2; ++ct) {
                        float z = acc2[rt][ct][reg];
                        float L = log1pf(expf(-fabsf(z)));
                        if (yn) lpos += fmaxf(-z, 0.f) + L;   // softplus(-z)
                        else    lneg += fmaxf(z, 0.f) + L;    // softplus(z)
                    }
                }
            }
#pragma unroll
        for (int off = 32; off >= 1; off >>= 1) {
            lpos += __shfl_down(lpos, off, 64);
            lneg += __shfl_down(lneg, off, 64);
        }
        if (l == 0) { redm[w][0] = lpos; redm[w][1] = lneg; }
        __syncthreads();
        if (t == 0) {
            atomicAdd(&accum[0], redm[0][0] + redm[1][0] + redm[2][0] + redm[3][0]);
            atomicAdd(&accum[1], redm[0][1] + redm[1][1] + redm[2][1] + redm[3][1]);
            int c = 0;
            for (int i = 0; i < 32; ++i) if (ylds[i] > 0) c++;
            if (c) atomicAdd(npos, c);
        }
    }
}

__global__ void finalize_kernel(const float* __restrict__ accum, const int* __restrict__ npos,
                                const int* __restrict__ flags, void* __restrict__ out, int N) {
    float np_ = (float)(*npos);
    float nn_ = (float)N - np_;
    float l2 = accum[0] / (fmaxf(np_, 1.f) * 128.f);
    float l1 = accum[1] / (fmaxf(nn_, 1.f) * 128.f);
    stf(out, 0, flags[2], l1 + l2);
}

// ---- launch ----------------------------------------------------------------

extern "C" void kernel_launch(void* const* d_in, const int* in_sizes, int n_in,
                              void* d_out, int out_size, void* d_ws, size_t ws_size,
                              hipStream_t stream) {
    const void* x    = d_in[0];
    const int* xedge = (const int*)d_in[1];
    const void* y    = d_in[2];
    const void* W1l  = d_in[4];
    const void* b1l  = d_in[5];
    const void* W1r  = d_in[6];
    const void* W2l  = d_in[7];
    const void* b2l  = d_in[8];
    const void* W2r  = d_in[9];
    const void* Wdec = d_in[10];

    const int N = in_sizes[0] / NDIM;
    const int E = in_sizes[1] / 2;

    char* ws = (char*)d_ws;
    size_t off = 0;
    auto alloc = [&](size_t bytes) -> void* {
        void* p = ws + off;
        off = (off + bytes + 255) & ~(size_t)255;
        return p;
    };
    int*   flags  = (int*)alloc(64);
    float* accum  = (float*)alloc(64);
    int*   npos   = (int*)alloc(64);
    int*   bsum   = (int*)alloc(1024 * 4);
    int*   boff   = (int*)alloc(1024 * 4);
    int*   cnt    = (int*)alloc((size_t)N * 4);
    int*   rowptr = (int*)alloc((size_t)(N + 1) * 4);
    int*   col    = (int*)alloc((size_t)E * 4);
    unsigned* xb  = (unsigned*)alloc((size_t)N * 64 * 4);
    unsigned* hbuf = (unsigned*)alloc((size_t)N * 64 * 4);
    short* T1l = (short*)alloc(NDIM * NDIM * 2);
    short* T1r = (short*)alloc(NDIM * NDIM * 2);
    short* T2l = (short*)alloc(NDIM * NDIM * 2);
    short* T2r = (short*)alloc(NDIM * NDIM * 2);
    short* Td  = (short*)alloc(NDIM * NDIM * 2);
    float* b1c = (float*)alloc(NDIM * 4);
    float* b2c = (float*)alloc(NDIM * 4);

    const int zb = (N + 255) / 256;
    detect_kernel<<<zb, 256, 0, stream>>>(xedge, (const unsigned int*)y,
                                          (const unsigned short*)x, flags, cnt,
                                          accum, npos, N);
    const long prep_items = (long)NDIM * NDIM + (long)N * 64;  // >> E
    prep_kernel<<<(int)((prep_items + 255) / 256), 256, 0, stream>>>(
        x, W1l, b1l, W1r, W2l, b2l, W2r, Wdec, flags,
        T1l, T1r, T2l, T2r, Td, b1c, b2c, xb, xedge, E, cnt, N);

    const int sb = (N + SCAN_CHUNK - 1) / SCAN_CHUNK;
    scan_partial<<<sb, 256, 0, stream>>>(cnt, bsum, N);
    scan_bsums<<<1, 1024, 0, stream>>>(bsum, boff, sb, rowptr, N);
    scan_scatter<<<sb, 256, 0, stream>>>(cnt, boff, rowptr, N);

    const int eb = (E + 255) / 256;
    fill_kernel<<<eb, 256, 0, stream>>>(xedge, E, flags, rowptr, cnt, col);

    const int nb32 = (N + 31) / 32;
    // layer 1: reads xb, writes hbuf (bf16x2)
    layer_mfma<true, 0><<<nb32, 256, 0, stream>>>(
        xb, rowptr, col, T1l, b1c, T1r, nullptr, nullptr, flags,
        hbuf, nullptr, nullptr, N);
    // layer 2 (fused): reads hbuf, writes d_out emb + loss partials
    layer_mfma<false, 1><<<nb32, 256, 0, stream>>>(
        hbuf, rowptr, col, T2l, b2c, T2r, Td, y, flags,
        d_out, accum, npos, N);
    finalize_kernel<<<1, 1, 0, stream>>>(accum, npos, flags, d_out, N);
}

// Round 11
// 359.647 us; speedup vs baseline: 1.2706x; 1.0274x over previous
//
#include <hip/hip_runtime.h>
#include <hip/hip_bf16.h>

#define NDIM 128
#define SCAN_CHUNK 1024  // per block: 256 threads x 4 elements

typedef __attribute__((ext_vector_type(8))) short short8;
typedef __attribute__((ext_vector_type(4))) float f32x4;

__device__ __forceinline__ float bf2f(__hip_bfloat16 v) { return __bfloat162float(v); }

__device__ __forceinline__ float ldf(const void* p, long i, int f32) {
    return f32 ? ((const float*)p)[i] : bf2f(((const __hip_bfloat16*)p)[i]);
}
__device__ __forceinline__ void stf(void* p, long i, int f32, float v) {
    if (f32) ((float*)p)[i] = v;
    else     ((__hip_bfloat16*)p)[i] = __float2bfloat16(v);
}
__device__ __forceinline__ short f2bf(float v) {
    __hip_bfloat16 h = __float2bfloat16(v);
    short s;
    __builtin_memcpy(&s, &h, 2);
    return s;
}
// bf16x2 packed in a uint: low halfword = even feature, high = odd feature
__device__ __forceinline__ float bflo(unsigned u) { u <<= 16; float f; __builtin_memcpy(&f, &u, 4); return f; }
__device__ __forceinline__ float bfhi(unsigned u) { u &= 0xffff0000u; float f; __builtin_memcpy(&f, &u, 4); return f; }
__device__ __forceinline__ unsigned packbf(float a, float b) {
    unsigned la = (unsigned short)f2bf(a);
    unsigned hb = (unsigned short)f2bf(b);
    return (hb << 16) | la;
}
// Swizzled LDS index (shorts) for A-tiles: 16B-chunk XOR by (row&7).
__device__ __forceinline__ int aswz(int m, int k) {
    return m * NDIM + ((((k >> 3) ^ (m & 7)) << 3) | (k & 7));
}
// Same swizzle at uint (bf16x2) granularity: p = feature-pair index 0..63.
__device__ __forceinline__ int wswz(int m, int p) {
    return m * 64 + ((((p >> 2) ^ (m & 7)) << 2) | (p & 3));
}

// ---- detect dtypes + zero cnt/accum/npos -----------------------------------
__global__ void detect_kernel(const int* __restrict__ xedge32,
                              const unsigned int* __restrict__ yw,
                              const unsigned short* __restrict__ xh,
                              int* __restrict__ flags, int* __restrict__ cnt,
                              float* __restrict__ accum, int* __restrict__ npos, int N) {
    const int gid = blockIdx.x * 256 + threadIdx.x;
    for (int i = gid; i < N; i += gridDim.x * 256) cnt[i] = 0;
    if (gid == 0) { accum[0] = 0.f; accum[1] = 0.f; npos[0] = 0; }
    if (blockIdx.x == 0) {
        __shared__ int se, sy, scount;
        const int t = threadIdx.x;
        if (t == 0) { se = 1; sy = 0; scount = 0; }
        __syncthreads();
        for (int i = t; i < 512; i += 256)
            if (xedge32[2 * i + 1] != 0) se = 0;
        for (int i = t; i < 1024; i += 256)
            if (yw[i] > 1u) sy = 1;
        int c = 0;
        for (int i = t; i < 1024; i += 256) {
            int ex = (xh[2 * i] >> 7) & 0xFF;
            if (ex >= 100 && ex <= 150) c++;
        }
        atomicAdd(&scount, c);
        __syncthreads();
        if (t == 0) { flags[0] = se; flags[1] = sy; flags[2] = (scount < 900) ? 1 : 0; }
    }
}

// ---- prep: weights + biases + canonical bf16x2 x + FUSED degree pass -------

__global__ void prep_kernel(const void* __restrict__ x,
                            const void* __restrict__ W1l, const void* __restrict__ b1l,
                            const void* __restrict__ W1r, const void* __restrict__ W2l,
                            const void* __restrict__ b2l, const void* __restrict__ W2r,
                            const void* __restrict__ Wd, const int* __restrict__ flags,
                            short* __restrict__ T1l, short* __restrict__ T1r,
                            short* __restrict__ T2l, short* __restrict__ T2r,
                            short* __restrict__ Td, float* __restrict__ b1c,
                            float* __restrict__ b2c, unsigned* __restrict__ xb,
                            const int* __restrict__ xedge, int E,
                            int* __restrict__ cnt, int N) {
    const int wf = flags[2];
    const long idx = (long)blockIdx.x * 256 + threadIdx.x;
    // fused degree pass (first E threads)
    if (idx < E) {
        int d = flags[0] ? xedge[2 * (E + idx)] : xedge[E + idx];
        atomicAdd(&cnt[d], 1);
    }
    if (idx < NDIM * NDIM) {
        int k = (int)(idx >> 7), n = (int)(idx & 127);
        int o = n * NDIM + k;
        T1l[o] = f2bf(ldf(W1l, idx, wf));
        T1r[o] = f2bf(ldf(W1r, idx, wf));
        T2l[o] = f2bf(ldf(W2l, idx, wf));
        T2r[o] = f2bf(ldf(W2r, idx, wf));
        Td [o] = f2bf(ldf(Wd , idx, wf));
        if (idx < NDIM) { b1c[idx] = ldf(b1l, idx, wf); b2c[idx] = ldf(b2l, idx, wf); }
    } else {
        long p = idx - NDIM * NDIM;
        long np = (long)N * 64;
        if (p < np) {
            if (wf) {
                float2 v = ((const float2*)x)[p];
                xb[p] = packbf(v.x, v.y);
            } else {
                xb[p] = ((const unsigned*)x)[p];
            }
        }
    }
}

// ---- 3-phase multi-block exclusive scan of cnt -> rowptr -------------------

__global__ void scan_partial(const int* __restrict__ cnt, int* __restrict__ bsum, int N) {
    __shared__ int red[256];
    const int t = threadIdx.x;
    const long base = (long)blockIdx.x * SCAN_CHUNK + (long)t * 4;
    int s = 0;
#pragma unroll
    for (int i = 0; i < 4; ++i) { long idx = base + i; if (idx < N) s += cnt[idx]; }
    red[t] = s;
    __syncthreads();
    for (int off = 128; off >= 1; off >>= 1) {
        if (t < off) red[t] += red[t + off];
        __syncthreads();
    }
    if (t == 0) bsum[blockIdx.x] = red[0];
}

__global__ void scan_bsums(const int* __restrict__ bsum, int* __restrict__ boff,
                           int B, int* __restrict__ rowptr, int N) {
    __shared__ int part[1024];
    const int t = threadIdx.x;
    int v = (t < B) ? bsum[t] : 0;
    part[t] = v;
    __syncthreads();
    for (int off = 1; off < 1024; off <<= 1) {
        int u = (t >= off) ? part[t - off] : 0;
        __syncthreads();
        part[t] += u;
        __syncthreads();
    }
    if (t < B) boff[t] = part[t] - v;
    if (t == 1023) rowptr[N] = part[1023];
}

__global__ void scan_scatter(int* __restrict__ cnt, const int* __restrict__ boff,
                             int* __restrict__ rowptr, int N) {
    __shared__ int tsum[256];
    const int t = threadIdx.x;
    const long base = (long)blockIdx.x * SCAN_CHUNK + (long)t * 4;
    int loc[4];
    int s = 0;
#pragma unroll
    for (int i = 0; i < 4; ++i) {
        long idx = base + i;
        int c = (idx < N) ? cnt[idx] : 0;
        loc[i] = s;
        s += c;
    }
    tsum[t] = s;
    __syncthreads();
    for (int off = 1; off < 256; off <<= 1) {
        int u = (t >= off) ? tsum[t - off] : 0;
        __syncthreads();
        tsum[t] += u;
        __syncthreads();
    }
    const int texcl = tsum[t] - s;
    const int b0 = boff[blockIdx.x];
#pragma unroll
    for (int i = 0; i < 4; ++i) {
        long idx = base + i;
        if (idx < N) { rowptr[idx] = b0 + texcl + loc[i]; cnt[idx] = 0; }
    }
}

__global__ void fill_kernel(const int* __restrict__ xedge, int E,
                            const int* __restrict__ flags, const int* __restrict__ rowptr,
                            int* __restrict__ cur, int* __restrict__ col) {
    int e = blockIdx.x * blockDim.x + threadIdx.x;
    if (e >= E) return;
    const int e64 = flags[0];
    int s = e64 ? xedge[2 * e] : xedge[e];
    int d = e64 ? xedge[2 * (E + e)] : xedge[E + e];
    int p = rowptr[d] + atomicAdd(&cur[d], 1);
    col[p] = s;
}

// ---- SAGE layer: round-6 unroll-8 gather -> LDS -> MFMA dual-GEMM ----------
// OUTMODE 0: bf16 out (outp=hbuf), LDS-staged coalesced store.
// OUTMODE 1: FUSED: emb direct-store (flag dtype at d_out+1elem) + decoder
//            MFMA + BCE loss accumulation.

template <bool RELU, int OUTMODE>
__global__ __launch_bounds__(256)
void layer_mfma(const unsigned* __restrict__ Xb, const int* __restrict__ rowptr,
                const int* __restrict__ col, const short* __restrict__ WlT,
                const float* __restrict__ biasc, const short* __restrict__ WrT,
                const short* __restrict__ WdT, const void* __restrict__ yv,
                const int* __restrict__ flags, void* __restrict__ outp,
                float* __restrict__ accum, int* __restrict__ npos, int N) {
    __shared__ short AS[2 * 32 * NDIM];  // [Ms 8KB][Ss 8KB]
    __shared__ int ylds[32];
    __shared__ float redm[4][2];
    short* Ms = AS;
    short* Ss = AS + 32 * NDIM;
    unsigned* Msw = (unsigned*)Ms;
    unsigned* Ssw = (unsigned*)Ss;
    const int t = threadIdx.x;
    const int n0 = blockIdx.x * 32;
    const int wf = flags[2];

    if (OUTMODE == 1 && t < 32) {
        const int yb = flags[1];
        int n = n0 + t;
        int yn = -1;
        if (n < N)
            yn = yb ? (int)((const unsigned char*)yv)[n]
                    : (((const int*)yv)[n] != 0 ? 1 : 0);
        ylds[t] = yn;
    }

    // ---- gather: 4 row-groups of 64 lanes; lane = feature-pair; unroll 8 ----
    // (round-6 form: 32 VGPR, ~50% occupancy — measured local optimum)
    {
        const int g = t >> 6, p = t & 63;
        for (int r = g; r < 32; r += 4) {
            int n = n0 + r;
            float m0 = 0.f, m1 = 0.f;
            unsigned su = 0;
            if (n < N) {
                int b = rowptr[n], e = rowptr[n + 1];
                int i = b;
                for (; i + 8 <= e; i += 8) {
                    unsigned u0 = Xb[(long)col[i    ] * 64 + p];
                    unsigned u1 = Xb[(long)col[i + 1] * 64 + p];
                    unsigned u2 = Xb[(long)col[i + 2] * 64 + p];
                    unsigned u3 = Xb[(long)col[i + 3] * 64 + p];
                    unsigned u4 = Xb[(long)col[i + 4] * 64 + p];
                    unsigned u5 = Xb[(long)col[i + 5] * 64 + p];
                    unsigned u6 = Xb[(long)col[i + 6] * 64 + p];
                    unsigned u7 = Xb[(long)col[i + 7] * 64 + p];
                    m0 += ((bflo(u0) + bflo(u1)) + (bflo(u2) + bflo(u3)))
                        + ((bflo(u4) + bflo(u5)) + (bflo(u6) + bflo(u7)));
                    m1 += ((bfhi(u0) + bfhi(u1)) + (bfhi(u2) + bfhi(u3)))
                        + ((bfhi(u4) + bfhi(u5)) + (bfhi(u6) + bfhi(u7)));
                }
                for (; i < e; ++i) {
                    unsigned u = Xb[(long)col[i] * 64 + p];
                    m0 += bflo(u);
                    m1 += bfhi(u);
                }
                float inv = 1.f / fmaxf((float)(e - b), 1.f);
                m0 *= inv; m1 *= inv;
                su = Xb[(long)n * 64 + p];
            }
            int wi = wswz(r, p);
            Msw[wi] = packbf(m0, m1);
            Ssw[wi] = su;
        }
    }
    __syncthreads();
    // ---- MFMA: wave w owns cols [w*32, w*32+32), 2x2 16x16x32 tiles ----
    const int l = t & 63, w = t >> 6;
    const int quad = l >> 4, l15 = l & 15;
    const int wcol = w * 32;
    f32x4 acc[2][2] = {};
    for (int k0 = 0; k0 < NDIM; k0 += 32) {
        const int kc = k0 + quad * 8;
        short8 ams[2], ass[2], bl[2], br[2];
#pragma unroll
        for (int rt = 0; rt < 2; ++rt) {
            int m = rt * 16 + l15;
            ams[rt] = *(const short8*)&Ms[aswz(m, kc)];
            ass[rt] = *(const short8*)&Ss[aswz(m, kc)];
        }
#pragma unroll
        for (int ct = 0; ct < 2; ++ct) {
            int n = wcol + ct * 16 + l15;
            bl[ct] = *(const short8*)&WlT[n * NDIM + kc];
            br[ct] = *(const short8*)&WrT[n * NDIM + kc];
        }
#pragma unroll
        for (int rt = 0; rt < 2; ++rt)
#pragma unroll
            for (int ct = 0; ct < 2; ++ct) {
                acc[rt][ct] = __builtin_amdgcn_mfma_f32_16x16x32_bf16(
                    ams[rt], bl[ct], acc[rt][ct], 0, 0, 0);
                acc[rt][ct] = __builtin_amdgcn_mfma_f32_16x16x32_bf16(
                    ass[rt], br[ct], acc[rt][ct], 0, 0, 0);
            }
    }
    __syncthreads();  // all MFMA LDS reads done; Ms/Ss reusable

    if (OUTMODE == 0) {
        // bf16 out tile row-major in Ms region, then coalesced uint store
#pragma unroll
        for (int ct = 0; ct < 2; ++ct) {
            int cg = wcol + ct * 16 + l15;
            float bv = biasc[cg];
#pragma unroll
            for (int rt = 0; rt < 2; ++rt)
#pragma unroll
                for (int reg = 0; reg < 4; ++reg) {
                    int row = rt * 16 + quad * 4 + reg;
                    float v = acc[rt][ct][reg] + bv;
                    if (RELU) v = fmaxf(v, 0.f);
                    Ms[row * NDIM + cg] = f2bf(v);
                }
        }
        __syncthreads();
        unsigned* ob = (unsigned*)outp;
        for (int idx = t; idx < 2048; idx += 256) {
            int r = idx >> 6;
            if (n0 + r < N) ob[(long)n0 * 64 + idx] = Msw[idx];
        }
    } else {
        // ---- fused: Abf into Ms (aswz) + direct emb store from registers ----
#pragma unroll
        for (int ct = 0; ct < 2; ++ct) {
            int cg = wcol + ct * 16 + l15;
            float bv = biasc[cg];
#pragma unroll
            for (int rt = 0; rt < 2; ++rt)
#pragma unroll
                for (int reg = 0; reg < 4; ++reg) {
                    int row = rt * 16 + quad * 4 + reg;
                    float v = acc[rt][ct][reg] + bv;
                    Ms[aswz(row, cg)] = f2bf(v);
                    int n = n0 + row;
                    if (n < N) {
                        if (wf) ((float*)outp)[1 + (long)n * NDIM + cg] = v;
                        else ((__hip_bfloat16*)outp)[1 + (long)n * NDIM + cg] =
                                 __float2bfloat16(v);
                    }
                }
        }
        __syncthreads();
        // ---- decoder GEMM from Abf(Ms) ----
        f32x4 acc2[2][2] = {};
        for (int k0 = 0; k0 < NDIM; k0 += 32) {
            const int kc = k0 + quad * 8;
            short8 a[2], b[2];
#pragma unroll
            for (int rt = 0; rt < 2; ++rt)
                a[rt] = *(const short8*)&Ms[aswz(rt * 16 + l15, kc)];
#pragma unroll
            for (int ct = 0; ct < 2; ++ct)
                b[ct] = *(const short8*)&WdT[(wcol + ct * 16 + l15) * NDIM + kc];
#pragma unroll
            for (int rt = 0; rt < 2; ++rt)
#pragma unroll
                for (int ct = 0; ct < 2; ++ct)
                    acc2[rt][ct] = __builtin_amdgcn_mfma_f32_16x16x32_bf16(
                        a[rt], b[ct], acc2[rt][ct], 0, 0, 0);
        }
        float lpos = 0.f, lneg = 0.f;
#pragma unroll
        for (int rt = 0; rt < 2; ++rt)
#pragma unroll
            for (int reg = 0; reg < 4; ++reg) {
                int row = rt * 16 + quad * 4 + reg;
                int yn = ylds[row];
                if (yn >= 0) {
#pragma unroll
                    for (int ct = 0; ct < 2; ++ct) {
                        float z = acc2[rt][ct][reg];
                        float L = log1pf(expf(-fabsf(z)));
                        if (yn) lpos += fmaxf(-z, 0.f) + L;   // softplus(-z)
                        else    lneg += fmaxf(z, 0.f) + L;    // softplus(z)
                    }
                }
            }
#pragma unroll
        for (int off = 32; off >= 1; off >>= 1) {
            lpos += __shfl_down(lpos, off, 64);
            lneg += __shfl_down(lneg, off, 64);
        }
        if (l == 0) { redm[w][0] = lpos; redm[w][1] = lneg; }
        __syncthreads();
        if (t == 0) {
            atomicAdd(&accum[0], redm[0][0] + redm[1][0] + redm[2][0] + redm[3][0]);
            atomicAdd(&accum[1], redm[0][1] + redm[1][1] + redm[2][1] + redm[3][1]);
            int c = 0;
            for (int i = 0; i < 32; ++i) if (ylds[i] > 0) c++;
            if (c) atomicAdd(npos, c);
        }
    }
}

__global__ void finalize_kernel(const float* __restrict__ accum, const int* __restrict__ npos,
                                const int* __restrict__ flags, void* __restrict__ out, int N) {
    float np_ = (float)(*npos);
    float nn_ = (float)N - np_;
    float l2 = accum[0] / (fmaxf(np_, 1.f) * 128.f);
    float l1 = accum[1] / (fmaxf(nn_, 1.f) * 128.f);
    stf(out, 0, flags[2], l1 + l2);
}

// ---- launch ----------------------------------------------------------------

extern "C" void kernel_launch(void* const* d_in, const int* in_sizes, int n_in,
                              void* d_out, int out_size, void* d_ws, size_t ws_size,
                              hipStream_t stream) {
    const void* x    = d_in[0];
    const int* xedge = (const int*)d_in[1];
    const void* y    = d_in[2];
    const void* W1l  = d_in[4];
    const void* b1l  = d_in[5];
    const void* W1r  = d_in[6];
    const void* W2l  = d_in[7];
    const void* b2l  = d_in[8];
    const void* W2r  = d_in[9];
    const void* Wdec = d_in[10];

    const int N = in_sizes[0] / NDIM;
    const int E = in_sizes[1] / 2;

    char* ws = (char*)d_ws;
    size_t off = 0;
    auto alloc = [&](size_t bytes) -> void* {
        void* p = ws + off;
        off = (off + bytes + 255) & ~(size_t)255;
        return p;
    };
    int*   flags  = (int*)alloc(64);
    float* accum  = (float*)alloc(64);
    int*   npos   = (int*)alloc(64);
    int*   bsum   = (int*)alloc(1024 * 4);
    int*   boff   = (int*)alloc(1024 * 4);
    int*   cnt    = (int*)alloc((size_t)N * 4);
    int*   rowptr = (int*)alloc((size_t)(N + 1) * 4);
    int*   col    = (int*)alloc((size_t)E * 4);
    unsigned* xb  = (unsigned*)alloc((size_t)N * 64 * 4);
    unsigned* hbuf = (unsigned*)alloc((size_t)N * 64 * 4);
    short* T1l = (short*)alloc(NDIM * NDIM * 2);
    short* T1r = (short*)alloc(NDIM * NDIM * 2);
    short* T2l = (short*)alloc(NDIM * NDIM * 2);
    short* T2r = (short*)alloc(NDIM * NDIM * 2);
    short* Td  = (short*)alloc(NDIM * NDIM * 2);
    float* b1c = (float*)alloc(NDIM * 4);
    float* b2c = (float*)alloc(NDIM * 4);

    const int zb = (N + 255) / 256;
    detect_kernel<<<zb, 256, 0, stream>>>(xedge, (const unsigned int*)y,
                                          (const unsigned short*)x, flags, cnt,
                                          accum, npos, N);
    const long prep_items = (long)NDIM * NDIM + (long)N * 64;  // >> E
    prep_kernel<<<(int)((prep_items + 255) / 256), 256, 0, stream>>>(
        x, W1l, b1l, W1r, W2l, b2l, W2r, Wdec, flags,
        T1l, T1r, T2l, T2r, Td, b1c, b2c, xb, xedge, E, cnt, N);

    const int sb = (N + SCAN_CHUNK - 1) / SCAN_CHUNK;
    scan_partial<<<sb, 256, 0, stream>>>(cnt, bsum, N);
    scan_bsums<<<1, 1024, 0, stream>>>(bsum, boff, sb, rowptr, N);
    scan_scatter<<<sb, 256, 0, stream>>>(cnt, boff, rowptr, N);

    const int eb = (E + 255) / 256;
    fill_kernel<<<eb, 256, 0, stream>>>(xedge, E, flags, rowptr, cnt, col);

    const int nb32 = (N + 31) / 32;
    // layer 1: reads xb, writes hbuf (bf16x2)
    layer_mfma<true, 0><<<nb32, 256, 0, stream>>>(
        xb, rowptr, col, T1l, b1c, T1r, nullptr, nullptr, flags,
        hbuf, nullptr, nullptr, N);
    // layer 2 (fused): reads hbuf, writes d_out emb + loss partials
    layer_mfma<false, 1><<<nb32, 256, 0, stream>>>(
        hbuf, rowptr, col, T2l, b2c, T2r, Td, y, flags,
        d_out, accum, npos, N);
    finalize_kernel<<<1, 1, 0, stream>>>(accum, npos, flags, d_out, N);
}